// Round 3
// baseline (52.069 us; speedup 1.0000x reference)
//
#include <hip/hip_runtime.h>

#define NUM_EMB 100000
#define DIM 128
#define TILE_E 32
#define BCAP 16  // bucket capacity; Poisson(2.05) tail beyond 16 ~ 1e-10/bin

typedef float f32x2 __attribute__((ext_vector_type(2)));
typedef float f32x4 __attribute__((ext_vector_type(4)));

// ---- d_ws layout (ints) ----
// [0, 100000)              cnt[e]
// 100000                   ovf_count
// [100004, 304804)         ovf list (lookup ids)
// [304816, 304816+1.6M)    bucket[e][BCAP]
#define WS_CNT 0
#define WS_OVFC 100000
#define WS_OVF 100004
#define WS_BUCKET 304816
#define WS_INTS_NEEDED (WS_BUCKET + NUM_EMB * BCAP)

// Pass A: bucket fill. p = position of lookup within its embedding's bucket.
__global__ __launch_bounds__(256) void bucket_fill_kernel(
    const int* __restrict__ idx, int* __restrict__ cnt,
    int* __restrict__ ovf_cnt, int* __restrict__ ovf, int* __restrict__ bucket,
    int n_lookups) {
  const int gid = blockIdx.x * 256 + threadIdx.x;
  if (gid >= n_lookups) return;
  const int e = idx[gid];
  const int p = atomicAdd(&cnt[e], 1);
  if (p < BCAP)
    bucket[e * BCAP + p] = gid;
  else
    ovf[atomicAdd(ovf_cnt, 1)] = gid;
}

// Pass B: per 32-embedding tile — coalesced W read, LDS transpose (+bias, f32),
// then scatter each bucketed lookup's output row as one contiguous 512B store.
__global__ __launch_bounds__(256) void fused_transpose_scatter_kernel(
    const float* __restrict__ W, const float* __restrict__ b,
    const int* __restrict__ cnt, const int* __restrict__ bucket,
    float* __restrict__ out) {
  __shared__ float tile[TILE_E][DIM + 2];  // stride 130 floats = 520B:
                                           // writes <=2-way (free), b64-aligned reads
  __shared__ int scnt[TILE_E];
  __shared__ int wl[TILE_E * BCAP];  // (e_local<<24)|n
  __shared__ int wl_total;
  const int t = threadIdx.x;
  const int e0 = blockIdx.x * TILE_E;

  if (t < TILE_E) {
    int c = cnt[e0 + t];
    scnt[t] = c < BCAP ? c : BCAP;
  }

  // Transpose load: 128 d-rows x 8 float4 of e. 8 lanes cover one 128B line.
#pragma unroll
  for (int k = 0; k < 4; ++k) {
    const int linear = k * 256 + t;  // 0..1023
    const int e4 = linear & 7;
    const int d = linear >> 3;  // 0..127
    const f32x4 v =
        *reinterpret_cast<const f32x4*>(&W[(size_t)d * NUM_EMB + e0 + e4 * 4]);
    const float bias = b[d];
    tile[e4 * 4 + 0][d] = v.x + bias;
    tile[e4 * 4 + 1][d] = v.y + bias;
    tile[e4 * 4 + 2][d] = v.z + bias;
    tile[e4 * 4 + 3][d] = v.w + bias;
  }
  __syncthreads();

  // Build worklist (first 32 threads): offsets via small LDS scan, then
  // pull bucket entries (avg 2/embedding; one 64B line per embedding).
  if (t < TILE_E) {
    int off = 0;
    for (int j = 0; j < t; ++j) off += scnt[j];
    const int c = scnt[t];
    for (int j = 0; j < c; ++j)
      wl[off + j] = (t << 24) | bucket[(e0 + t) * BCAP + j];
    if (t == TILE_E - 1) wl_total = off + c;
  }
  __syncthreads();

  // Scatter: one full wave per output row; f32x2/lane = 512B contiguous.
  const int R = wl_total;
  const int lane = t & 63;
  for (int r = (t >> 6); r < R; r += 4) {
    const int ent = wl[r];
    const int n = ent & 0xFFFFFF;
    const int el = ent >> 24;
    const f32x2 v = *reinterpret_cast<const f32x2*>(&tile[el][lane * 2]);
    __builtin_nontemporal_store(
        v, reinterpret_cast<f32x2*>(&out[(size_t)n * DIM + lane * 2]));
  }
}

// Pass C: fix the (expected zero) overflow entries with direct strided reads.
__global__ __launch_bounds__(256) void overflow_fix_kernel(
    const int* __restrict__ ovf_cnt, const int* __restrict__ ovf,
    const int* __restrict__ idx, const float* __restrict__ W,
    const float* __restrict__ b, float* __restrict__ out) {
  const int c = *ovf_cnt;
  const int gwave = (blockIdx.x * 256 + threadIdx.x) >> 6;
  const int nwaves = (gridDim.x * 256) >> 6;
  const int lane = threadIdx.x & 63;
  for (int i = gwave; i < c; i += nwaves) {
    const int n = ovf[i];
    const int e = idx[n];
#pragma unroll
    for (int h = 0; h < 2; ++h) {
      const int d = lane + h * 64;
      out[(size_t)n * DIM + d] = W[(size_t)d * NUM_EMB + e] + b[d];
    }
  }
}

// Fallback (ws too small): direct scattered gather, correct but slow.
__global__ __launch_bounds__(256) void direct_gather_kernel(
    const int* __restrict__ idx, const float* __restrict__ W,
    const float* __restrict__ b, float* __restrict__ out, long total) {
  long gid = (long)blockIdx.x * 256 + threadIdx.x;
  const long stride = (long)gridDim.x * 256;
  for (; gid < total; gid += stride) {
    const int d = (int)(gid & (DIM - 1));
    const long n = gid >> 7;
    out[gid] = W[(size_t)d * NUM_EMB + idx[n]] + b[d];
  }
}

extern "C" void kernel_launch(void* const* d_in, const int* in_sizes, int n_in,
                              void* d_out, int out_size, void* d_ws,
                              size_t ws_size, hipStream_t stream) {
  const int* idx = (const int*)d_in[0];    // [204800]
  const float* W = (const float*)d_in[1];  // [128][100000]
  const float* b = (const float*)d_in[2];  // [128]
  float* out = (float*)d_out;              // [204800][128]
  const int n_lookups = in_sizes[0];

  if (ws_size >= (size_t)WS_INTS_NEEDED * sizeof(int)) {
    int* ws = (int*)d_ws;
    int* cnt = ws + WS_CNT;
    int* ovfc = ws + WS_OVFC;
    int* ovf = ws + WS_OVF;
    int* bucket = ws + WS_BUCKET;
    // zero cnt[100000] + ovf_count (contiguous prefix of ws)
    hipMemsetAsync(d_ws, 0, (size_t)(NUM_EMB + 1) * sizeof(int), stream);
    bucket_fill_kernel<<<(n_lookups + 255) / 256, 256, 0, stream>>>(
        idx, cnt, ovfc, ovf, bucket, n_lookups);
    fused_transpose_scatter_kernel<<<NUM_EMB / TILE_E, 256, 0, stream>>>(
        W, b, cnt, bucket, out);
    overflow_fix_kernel<<<4, 256, 0, stream>>>(ovfc, ovf, idx, W, b, out);
  } else {
    const long total = (long)n_lookups * DIM;
    int blocks = (int)((total + 255) / 256);
    if (blocks > 2048) blocks = 2048;
    direct_gather_kernel<<<blocks, 256, 0, stream>>>(idx, W, b, out, total);
  }
}